// Round 7
// baseline (312.994 us; speedup 1.0000x reference)
//
#include <hip/hip_runtime.h>
#include <stdint.h>

typedef unsigned short u16;
typedef short bf16x8 __attribute__((ext_vector_type(8)));
typedef float f32x4 __attribute__((ext_vector_type(4)));

#define CTX 2048
#define DIN 1024
#define DOUT 1024
#define NB 8

__device__ __forceinline__ u16 f2bf(float f) {
  uint32_t u = __builtin_bit_cast(uint32_t, f);
  u += 0x7FFFu + ((u >> 16) & 1u);
  return (u16)(u >> 16);
}

// global -> LDS async, 16B per lane. LDS dest is wave-uniform base + lane*16.
__device__ __forceinline__ void gld_lds16(const u16* g, const u16* lds) {
  __builtin_amdgcn_global_load_lds(
      (const __attribute__((address_space(1))) uint32_t*)(unsigned long long)(const void*)g,
      (__attribute__((address_space(3))) uint32_t*)(uint32_t)(unsigned long long)(const void*)lds,
      16, 0, 0);
}

#define SBAR() asm volatile("s_barrier" ::: "memory")
#define VMCNT4() asm volatile("s_waitcnt vmcnt(4)" ::: "memory")
#define VMCNT0() asm volatile("s_waitcnt vmcnt(0)" ::: "memory")
#define LGKM0() asm volatile("s_waitcnt lgkmcnt(0)" ::: "memory")
#define SCHED0() __builtin_amdgcn_sched_barrier(0)

// ---------------------------------------------------------------------------
// 256x256-tile GEMM, bf16, BK=64, 512 thr = 8 waves (2Mx4N), m201 phase order.
// Per phase: {ds_reads for THIS phase's MFMA; stage 1 half-tile; s_barrier;
// lgkmcnt(0); setprio(1); 16 MFMA; setprio(0); s_barrier}. All waves fill the
// DS queue before the barrier; FIFO lgkm completion staggers MFMA starts so
// DS drain overlaps matrix work (round-6 lesson: reads issued after the MFMA
// cluster serialize the pipes).
// LDS: 2 bufs x 4 regions (A0,A1,B0,B1) x 16KB, fragment-order, conflict-free
// (SQ_LDS_BANK_CONFLICT == 0 measured).
// Phases of tile T (buf b): P0 reads arLo+brA, stages B0(T+1); P1 reads arHi,
// stages B1(T+1); P2 reads brB (overwrites brA regs), stages A0(T+2); P3 no
// reads, stages A1(T+2), boundary vmcnt.
// LDS write-safety: stage A(T+2) into buf b regions A0/A1 is issued in P2/P3,
// strictly after ALL waves passed P1-end barrier, i.e. after every wave's
// arLo/arHi reads completed (lgkmcnt(0) gated) -- no read/overwrite race.
// vmcnt ledger (round-4-verified, re-derived): after prologue 4 in flight
// (A(T=1)); +2 per phase -> 12 at P3 end; vmcnt(4) retires the 8 tile-(T+1)
// loads, leaves A(T+2). When T+2>=nkt: 8 in flight all tile-(T+1) -> vmcnt(0).
// Requires nkt >= 2 and even (all call sites: nkt in {4..32}, even).
// ---------------------------------------------------------------------------
template <typename EPI>
__device__ __forceinline__ void gemm256(const u16* __restrict__ A, int lda,
                                        const u16* __restrict__ Bt, int ldb,
                                        int m0, int n0, int K, EPI&& epi) {
  __shared__ __align__(16) u16 lds[65536];  // [buf2][region4][block16][512]

  const int t = threadIdx.x;
  const int lane = t & 63;
  const int w = t >> 6;     // 0..7
  const int wm = w >> 2;    // 0..1 (m half)
  const int wn = w & 3;     // 0..3 (n col group)
  const int l15 = lane & 15;
  const int l16 = lane >> 4;
  const int nkt = K >> 6;
  const int bf0 = (wn & 1) * 4;  // frag base within B region

  f32x4 acc[8][4];
#pragma unroll
  for (int i = 0; i < 8; ++i)
#pragma unroll
    for (int j = 0; j < 4; ++j) acc[i][j] = {0.f, 0.f, 0.f, 0.f};

  const u16* gA0 = A + (size_t)(m0 + w * 16 + l15) * lda + l16 * 8;
  const u16* gA1 = gA0 + (size_t)128 * lda;
  const u16* gB0 = Bt + (size_t)(n0 + w * 16 + l15) * ldb + l16 * 8;
  const u16* gB1 = gB0 + (size_t)128 * ldb;

  auto STAGEH = [&](int bb, int rr, const u16* g) {
    u16* d = lds + (((bb * 4 + rr) * 16) + w * 2) * 512;
    gld_lds16(g, d);             // kstep 0: cols +0..31
    gld_lds16(g + 32, d + 512);  // kstep 1: cols +32..63
  };

  // prologue: tile 0 fully + tile 1's A halves
  STAGEH(0, 0, gA0);
  STAGEH(0, 1, gA1);
  STAGEH(0, 2, gB0);
  STAGEH(0, 3, gB1);
  if (nkt > 1) {
    STAGEH(1, 0, gA0 + 64);
    STAGEH(1, 1, gA1 + 64);
  }
  VMCNT4();  // tile 0's 8 loads landed; tile-1-A's 4 in flight
  SBAR();

  bf16x8 arLo[4][2], arHi[4][2], br[2][2];

  auto kbody = [&](int T, int b) {
    const u16* bufA = lds + ((b * 4 + wm) * 16) * 512 + lane * 8;
    const u16* bufB = lds + ((b * 4 + 2 + (wn >> 1)) * 16) * 512 + lane * 8;

    // ---- P0: read arLo + brA; stage B0(T+1); bar; lgkm0; MFMA C0; bar
#pragma unroll
    for (int fr = 0; fr < 4; ++fr)
#pragma unroll
      for (int ks = 0; ks < 2; ++ks)
        arLo[fr][ks] = *reinterpret_cast<const bf16x8*>(bufA + (fr * 2 + ks) * 512);
#pragma unroll
    for (int nc = 0; nc < 2; ++nc)
#pragma unroll
      for (int ks = 0; ks < 2; ++ks)
        br[nc][ks] = *reinterpret_cast<const bf16x8*>(bufB + ((bf0 + nc) * 2 + ks) * 512);
    if (T + 1 < nkt) STAGEH(b ^ 1, 2, gB0 + (size_t)(T + 1) * 64);
    SBAR();
    LGKM0();
    SCHED0();
    __builtin_amdgcn_s_setprio(1);
#pragma unroll
    for (int fr = 0; fr < 4; ++fr)
#pragma unroll
      for (int nc = 0; nc < 2; ++nc)
#pragma unroll
        for (int ks = 0; ks < 2; ++ks)
          acc[fr][nc] = __builtin_amdgcn_mfma_f32_16x16x32_bf16(arLo[fr][ks], br[nc][ks],
                                                                acc[fr][nc], 0, 0, 0);
    __builtin_amdgcn_s_setprio(0);
    SBAR();

    // ---- P1: read arHi; stage B1(T+1); bar; lgkm0; MFMA C1 = arHi x brA; bar
#pragma unroll
    for (int fr = 0; fr < 4; ++fr)
#pragma unroll
      for (int ks = 0; ks < 2; ++ks)
        arHi[fr][ks] = *reinterpret_cast<const bf16x8*>(bufA + ((fr + 4) * 2 + ks) * 512);
    if (T + 1 < nkt) STAGEH(b ^ 1, 3, gB1 + (size_t)(T + 1) * 64);
    SBAR();
    LGKM0();
    SCHED0();
    __builtin_amdgcn_s_setprio(1);
#pragma unroll
    for (int fr = 0; fr < 4; ++fr)
#pragma unroll
      for (int nc = 0; nc < 2; ++nc)
#pragma unroll
        for (int ks = 0; ks < 2; ++ks)
          acc[4 + fr][nc] = __builtin_amdgcn_mfma_f32_16x16x32_bf16(arHi[fr][ks], br[nc][ks],
                                                                    acc[4 + fr][nc], 0, 0, 0);
    __builtin_amdgcn_s_setprio(0);
    SBAR();

    // ---- P2: read brB (overwrite br); stage A0(T+2); bar; lgkm0; MFMA C2; bar
#pragma unroll
    for (int nc = 0; nc < 2; ++nc)
#pragma unroll
      for (int ks = 0; ks < 2; ++ks)
        br[nc][ks] = *reinterpret_cast<const bf16x8*>(bufB + ((bf0 + 2 + nc) * 2 + ks) * 512);
    if (T + 2 < nkt) STAGEH(b, 0, gA0 + (size_t)(T + 2) * 64);
    SBAR();
    LGKM0();
    SCHED0();
    __builtin_amdgcn_s_setprio(1);
#pragma unroll
    for (int fr = 0; fr < 4; ++fr)
#pragma unroll
      for (int nc = 0; nc < 2; ++nc)
#pragma unroll
        for (int ks = 0; ks < 2; ++ks)
          acc[4 + fr][2 + nc] = __builtin_amdgcn_mfma_f32_16x16x32_bf16(arHi[fr][ks], br[nc][ks],
                                                                        acc[4 + fr][2 + nc], 0, 0, 0);
    __builtin_amdgcn_s_setprio(0);
    SBAR();

    // ---- P3: no reads; stage A1(T+2); bar; MFMA C3 = arLo x brB; vmcnt; bar
    if (T + 2 < nkt) STAGEH(b, 1, gA1 + (size_t)(T + 2) * 64);
    SBAR();
    __builtin_amdgcn_s_setprio(1);
#pragma unroll
    for (int fr = 0; fr < 4; ++fr)
#pragma unroll
      for (int nc = 0; nc < 2; ++nc)
#pragma unroll
        for (int ks = 0; ks < 2; ++ks)
          acc[fr][2 + nc] = __builtin_amdgcn_mfma_f32_16x16x32_bf16(arLo[fr][ks], br[nc][ks],
                                                                    acc[fr][2 + nc], 0, 0, 0);
    __builtin_amdgcn_s_setprio(0);
    if (T + 2 < nkt) {
      VMCNT4();  // retires tile-(T+1)'s 8 loads, leaves A(T+2)
    } else {
      VMCNT0();  // no A(T+2) staged: drain so tile T+1 (if any) is landed
    }
    SBAR();
  };

  for (int TT = 0; TT < nkt; TT += 2) {  // nkt even at all call sites
    kbody(TT, 0);
    kbody(TT + 1, 1);
  }

  // epilogue: row = r0 + fr*16 + i, col = c0 + nc*16 (tile-local)
  epi(acc, wm * 128 + l16 * 4, wn * 64 + l15);
}

// ---------------------------------------------------------------------------
__global__ __launch_bounds__(256) void k_cvt_x(const float* __restrict__ x,
                                               u16* __restrict__ xb) {
  const int idx = (blockIdx.x * 256 + threadIdx.x) * 4;
  const float4 v = *reinterpret_cast<const float4*>(x + idx);
  ushort4 o;
  o.x = f2bf(v.x); o.y = f2bf(v.y); o.z = f2bf(v.z); o.w = f2bf(v.w);
  *reinterpret_cast<ushort4*>(xb + idx) = o;
}

// W [DIN][DOUT] fp32 -> Wt [DOUT][DIN] bf16 (tiled transpose via LDS)
__global__ __launch_bounds__(256) void k_cvt_wt(const float* __restrict__ W,
                                                u16* __restrict__ Wt) {
  __shared__ u16 tile[64][65];
  const int bc = blockIdx.x;
  const int tr0 = (bc >> 4) * 64;
  const int tc0 = (bc & 15) * 64;
  const int t = threadIdx.x;
  const int col = t & 63, rr = t >> 6;
#pragma unroll
  for (int p = 0; p < 16; ++p) {
    const int row = rr * 16 + p;
    tile[row][col] = f2bf(W[(size_t)(tr0 + row) * DOUT + tc0 + col]);
  }
  __syncthreads();
#pragma unroll
  for (int p = 0; p < 16; ++p) {
    const int row = rr * 16 + p;
    Wt[(size_t)(tc0 + row) * DIN + tr0 + col] = tile[col][row];
  }
}

// Fused QKV projection. 768 blocks, XCD-swizzled; n-tiles 0-7 -> qk row-major,
// 8-11 -> vT transposed.
__global__ __launch_bounds__(512, 2) void k_proj(const u16* __restrict__ xb,
                                                 const u16* __restrict__ Wt,
                                                 u16* __restrict__ qkb,
                                                 u16* __restrict__ vT) {
  const int wg = (blockIdx.x & 7) * 96 + (blockIdx.x >> 3);  // bijective, 768%8==0
  const int m0 = (wg / 12) * 256, n0 = (wg % 12) * 256;
  gemm256(xb, DIN, Wt, DIN, m0, n0, DIN,
          [&](const f32x4(&acc)[8][4], int r0, int c0) {
            if (n0 < 2 * DOUT) {  // q or k -> qkb row-major [16384][2048]
#pragma unroll
              for (int fr = 0; fr < 8; ++fr)
#pragma unroll
                for (int nc = 0; nc < 4; ++nc) {
                  const int r = m0 + r0 + fr * 16;
                  const int c = n0 + c0 + nc * 16;
#pragma unroll
                  for (int i = 0; i < 4; ++i)
                    qkb[(size_t)(r + i) * 2048 + c] = f2bf(acc[fr][nc][i]);
                }
            } else {  // v -> vT[b][d][s]
              const int b = m0 >> 11;
              const int sl = (m0 & (CTX - 1)) + r0;
              u16* C = vT + (size_t)b * DOUT * CTX;
#pragma unroll
              for (int fr = 0; fr < 8; ++fr)
#pragma unroll
                for (int nc = 0; nc < 4; ++nc) {
                  const int d = n0 - 2 * DOUT + c0 + nc * 16;
                  const int s = sl + fr * 16;
                  ushort4 o;
                  o.x = f2bf(acc[fr][nc][0]);
                  o.y = f2bf(acc[fr][nc][1]);
                  o.z = f2bf(acc[fr][nc][2]);
                  o.w = f2bf(acc[fr][nc][3]);
                  *reinterpret_cast<ushort4*>(C + (size_t)d * CTX + s) = o;
                }
            }
          });
}

// S[b][i][j] = (q.k)/32, lower-triangular 256x256 tiles (36 per batch)
__global__ __launch_bounds__(512, 2) void k_score(const u16* __restrict__ qkb,
                                                  float* __restrict__ S) {
  const int u = (blockIdx.x & 7) * 36 + (blockIdx.x >> 3);  // 288%8==0
  const int b = u / 36, v = u % 36;
  int it = 0;
  while ((it + 1) * (it + 2) / 2 <= v) ++it;
  const int jt = v - it * (it + 1) / 2;
  const u16* Aq = qkb + (size_t)b * CTX * 2048;
  float* C = S + ((size_t)b << 22);
  const int m0 = it * 256, n0 = jt * 256;
  gemm256(Aq, 2048, Aq + 1024, 2048, m0, n0, DOUT,
          [&](const f32x4(&acc)[8][4], int r0, int c0) {
#pragma unroll
            for (int fr = 0; fr < 8; ++fr)
#pragma unroll
              for (int nc = 0; nc < 4; ++nc) {
                const int r = m0 + r0 + fr * 16;
                const int c = n0 + c0 + nc * 16;
#pragma unroll
                for (int i = 0; i < 4; ++i)
                  C[(size_t)(r + i) * CTX + c] = acc[fr][nc][i] * 0.03125f;
              }
          });
}

// row softmax over S fp32, write P bf16 in place (row stride 4096 u16),
// full 2048 cols written (zeros above diagonal) so PV GEMM needs no masking.
__global__ __launch_bounds__(256) void k_softmax(float* __restrict__ Sws) {
  const int row = blockIdx.x;
  const int b = row >> 11, i = row & (CTX - 1);
  const float* srow = Sws + ((size_t)b << 22) + ((size_t)i << 11);
  u16* prow = (u16*)(Sws + ((size_t)b << 22)) + ((size_t)i << 12);
  const int t = threadIdx.x;
  const int j0 = t * 8;
  float vv[8];
  if (j0 <= i) {
    const float4 v0 = *reinterpret_cast<const float4*>(srow + j0);
    const float4 v1 = *reinterpret_cast<const float4*>(srow + j0 + 4);
    vv[0] = v0.x; vv[1] = v0.y; vv[2] = v0.z; vv[3] = v0.w;
    vv[4] = v1.x; vv[5] = v1.y; vv[6] = v1.z; vv[7] = v1.w;
  } else {
#pragma unroll
    for (int p = 0; p < 8; ++p) vv[p] = -3.0e38f;
  }
  float mx = -3.0e38f;
#pragma unroll
  for (int p = 0; p < 8; ++p) {
    vv[p] = (j0 + p <= i) ? vv[p] : -3.0e38f;
    mx = fmaxf(mx, vv[p]);
  }
#pragma unroll
  for (int off = 32; off > 0; off >>= 1) mx = fmaxf(mx, __shfl_xor(mx, off));
  __shared__ float redm[4], reds[4];
  const int lane = t & 63, wid = t >> 6;
  if (lane == 0) redm[wid] = mx;
  __syncthreads();
  mx = fmaxf(fmaxf(redm[0], redm[1]), fmaxf(redm[2], redm[3]));
  float e[8], s = 0.f;
#pragma unroll
  for (int p = 0; p < 8; ++p) {
    e[p] = __expf(vv[p] - mx);
    s += e[p];
  }
#pragma unroll
  for (int off = 32; off > 0; off >>= 1) s += __shfl_xor(s, off);
  if (lane == 0) reds[wid] = s;
  __syncthreads();  // orders row reads above before in-place writes below
  s = reds[0] + reds[1] + reds[2] + reds[3];
  const float inv = 1.0f / s;
  ushort4 o0, o1;
  o0.x = (j0 + 0 <= i) ? f2bf(e[0] * inv) : (u16)0;
  o0.y = (j0 + 1 <= i) ? f2bf(e[1] * inv) : (u16)0;
  o0.z = (j0 + 2 <= i) ? f2bf(e[2] * inv) : (u16)0;
  o0.w = (j0 + 3 <= i) ? f2bf(e[3] * inv) : (u16)0;
  o1.x = (j0 + 4 <= i) ? f2bf(e[4] * inv) : (u16)0;
  o1.y = (j0 + 5 <= i) ? f2bf(e[5] * inv) : (u16)0;
  o1.z = (j0 + 6 <= i) ? f2bf(e[6] * inv) : (u16)0;
  o1.w = (j0 + 7 <= i) ? f2bf(e[7] * inv) : (u16)0;
  *reinterpret_cast<ushort4*>(prow + j0) = o0;
  *reinterpret_cast<ushort4*>(prow + j0 + 4) = o1;
}

// out[b][i][d] = sum_j P[b][i][j] * V[b][j][d]; K causally limited; LPT order.
__global__ __launch_bounds__(512, 2) void k_out(const float* __restrict__ Sws,
                                                const u16* __restrict__ vT,
                                                float* __restrict__ out) {
  const int idx = blockIdx.x;          // 256 blocks = 8it x 8b x 4nt
  const int it = 7 - (idx >> 5);       // longest (K=2048) first
  const int b = (idx >> 2) & 7;
  const int nt = idx & 3;
  const u16* P = (const u16*)(Sws + ((size_t)b << 22));  // lda = 4096 u16
  const u16* Bt = vT + (size_t)b * DOUT * CTX;           // [D][S]
  float* C = out + (size_t)b * CTX * DOUT;
  const int m0 = it * 256, n0 = nt * 256;
  gemm256(P, 2 * CTX, Bt, CTX, m0, n0, (it + 1) * 256,
          [&](const f32x4(&acc)[8][4], int r0, int c0) {
#pragma unroll
            for (int fr = 0; fr < 8; ++fr)
#pragma unroll
              for (int nc = 0; nc < 4; ++nc) {
                const int r = m0 + r0 + fr * 16;
                const int c = n0 + c0 + nc * 16;
#pragma unroll
                for (int i = 0; i < 4; ++i)
                  C[(size_t)(r + i) * DOUT + c] = acc[fr][nc][i];
              }
          });
}

// ---------------------------------------------------------------------------
extern "C" void kernel_launch(void* const* d_in, const int* in_sizes, int n_in,
                              void* d_out, int out_size, void* d_ws, size_t ws_size,
                              hipStream_t stream) {
  (void)in_sizes; (void)n_in; (void)out_size; (void)ws_size;
  const float* x = (const float*)d_in[0];
  const float* Wq = (const float*)d_in[1];
  const float* Wk = (const float*)d_in[2];
  const float* Wv = (const float*)d_in[3];
  float* out = (float*)d_out;
  uint8_t* ws = (uint8_t*)d_ws;

  // ws layout (224 MB):
  //   [0,128M): S fp32 [8][2048][2048] (P bf16 written in place by softmax)
  //     xb bf16 (32MB) + Wt_all (6MB) overlap S -- dead before k_score runs
  //   [128M,192M): qkb bf16 [8][2048][2048] (q cols 0..1023, k cols 1024..2047)
  //   [192M,224M): vT bf16 [8][1024][2048]
  float* S = (float*)ws;
  u16* xb = (u16*)ws;
  u16* Wt_all = (u16*)(ws + 33554432ull);  // [3072][1024]: q|k|v
  u16* qkb = (u16*)(ws + 134217728ull);
  u16* vT = (u16*)(ws + 201326592ull);

  k_cvt_x<<<16384, 256, 0, stream>>>(x, xb);
  k_cvt_wt<<<256, 256, 0, stream>>>(Wq, Wt_all);
  k_cvt_wt<<<256, 256, 0, stream>>>(Wk, Wt_all + 1024ull * 1024);
  k_cvt_wt<<<256, 256, 0, stream>>>(Wv, Wt_all + 2048ull * 1024);
  k_proj<<<768, 512, 0, stream>>>(xb, Wt_all, qkb, vT);
  k_score<<<288, 512, 0, stream>>>(qkb, S);
  k_softmax<<<NB * CTX, 256, 0, stream>>>(S);
  k_out<<<256, 512, 0, stream>>>(S, vT, out);
}